// Round 1
// baseline (5520.784 us; speedup 1.0000x reference)
//
#include <hip/hip_runtime.h>
#include <hip/hip_bf16.h>
#include <hip/hip_cooperative_groups.h>

namespace cg = cooperative_groups;

static constexpr int LL = 256;   // sequence length / nodes
static constexpr int BB = 128;   // batch
static constexpr int DD = 512;   // input dim
static constexpr int HHH = 512;  // hidden dim

typedef __attribute__((ext_vector_type(8))) short bf16x8;
typedef __attribute__((ext_vector_type(4))) float f32x4;
typedef __attribute__((ext_vector_type(8))) unsigned short u16x8;
typedef __attribute__((ext_vector_type(4))) unsigned short u16x4;

__device__ __forceinline__ unsigned short f2bf(float f) {
  union { float f; unsigned u; } v; v.f = f;
  unsigned r = (v.u + 0x7FFFu + ((v.u >> 16) & 1u)) >> 16;
  return (unsigned short)r;
}
__device__ __forceinline__ float bf2f(unsigned short s) {
  union { unsigned u; float f; } v; v.u = ((unsigned)s) << 16;
  return v.f;
}
__device__ __forceinline__ float sigm(float x) { return 1.0f / (1.0f + __expf(-x)); }
__device__ __forceinline__ float tanh_f(float x) { return 1.0f - 2.0f / (__expf(2.0f * x) + 1.0f); }

// ---------------------------------------------------------------------------
// Kernel 1: cast the 8 weight matrices (each 512x512 f32, row-major [out][in])
// to bf16.  wx = [Wi_x;Wf_x;Wo_x;Wu_x]  wh = [Wi_h;Wf_h;Wo_h;Wu_h]
// ---------------------------------------------------------------------------
__global__ __launch_bounds__(256) void wcast(
    const float* __restrict__ s0, const float* __restrict__ s1,
    const float* __restrict__ s2, const float* __restrict__ s3,
    const float* __restrict__ s4, const float* __restrict__ s5,
    const float* __restrict__ s6, const float* __restrict__ s7,
    unsigned short* __restrict__ wx, unsigned short* __restrict__ wh) {
  int gid = blockIdx.x * 256 + threadIdx.x;
  int e = gid * 4;
  int m = e >> 18;            // which of 8 matrices (512*512 = 262144 elems)
  int off = e & 0x3FFFF;
  const float* srcs[8] = {s0, s1, s2, s3, s4, s5, s6, s7};
  float4 v = *(const float4*)(srcs[m] + off);
  u16x4 o;
  o[0] = f2bf(v.x); o[1] = f2bf(v.y); o[2] = f2bf(v.z); o[3] = f2bf(v.w);
  unsigned short* dst = (m < 4) ? (wx + (size_t)m * 262144 + off)
                                : (wh + (size_t)(m - 4) * 262144 + off);
  *(u16x4*)dst = o;
}

// ---------------------------------------------------------------------------
// Kernel 2: Xpre[t*B+b][g*512+h] = x[t,b,:] . Wg_x[h,:] + bias_g[h]   (bf16)
// GEMM M=32768 N=2048 K=512, A = inputs f32 (converted on stage),
// B = wx bf16 (K-major rows).  64x64 tile, BK=64, 4 waves (16 rows each).
// ---------------------------------------------------------------------------
__global__ __launch_bounds__(256) void xproj(
    const float* __restrict__ X, const unsigned short* __restrict__ Wx,
    const float* __restrict__ bi_x, const float* __restrict__ bi_h,
    const float* __restrict__ bf_x, const float* __restrict__ bf_h,
    unsigned short* __restrict__ Xpre) {
  __shared__ unsigned short As[64][72];   // +8 pad: conflict-free ds_read_b128
  __shared__ unsigned short Bs[64][72];
  const int m0 = blockIdx.x * 64;
  const int n0 = blockIdx.y * 64;
  const int tid = threadIdx.x;
  const int r = tid >> 2, c4 = tid & 3;
  const int lane = tid & 63, w = tid >> 6;
  f32x4 acc[4] = {};
  for (int kt = 0; kt < 8; ++kt) {
    const int k0 = kt * 64;
    __syncthreads();
    {
      const float* src = X + (size_t)(m0 + r) * 512 + k0 + c4 * 16;
      float4 v0 = ((const float4*)src)[0];
      float4 v1 = ((const float4*)src)[1];
      float4 v2 = ((const float4*)src)[2];
      float4 v3 = ((const float4*)src)[3];
      u16x8 p0, p1;
      p0[0] = f2bf(v0.x); p0[1] = f2bf(v0.y); p0[2] = f2bf(v0.z); p0[3] = f2bf(v0.w);
      p0[4] = f2bf(v1.x); p0[5] = f2bf(v1.y); p0[6] = f2bf(v1.z); p0[7] = f2bf(v1.w);
      p1[0] = f2bf(v2.x); p1[1] = f2bf(v2.y); p1[2] = f2bf(v2.z); p1[3] = f2bf(v2.w);
      p1[4] = f2bf(v3.x); p1[5] = f2bf(v3.y); p1[6] = f2bf(v3.z); p1[7] = f2bf(v3.w);
      *(u16x8*)&As[r][c4 * 16] = p0;
      *(u16x8*)&As[r][c4 * 16 + 8] = p1;
      const unsigned short* sb = Wx + (size_t)(n0 + r) * 512 + k0 + c4 * 16;
      u16x8 q0 = ((const u16x8*)sb)[0];
      u16x8 q1 = ((const u16x8*)sb)[1];
      *(u16x8*)&Bs[r][c4 * 16] = q0;
      *(u16x8*)&Bs[r][c4 * 16 + 8] = q1;
    }
    __syncthreads();
#pragma unroll
    for (int kk = 0; kk < 64; kk += 32) {
      const int ko = kk + 8 * (lane >> 4);
      bf16x8 af = *(const bf16x8*)&As[w * 16 + (lane & 15)][ko];
#pragma unroll
      for (int n = 0; n < 4; ++n) {
        bf16x8 bfr = *(const bf16x8*)&Bs[n * 16 + (lane & 15)][ko];
        acc[n] = __builtin_amdgcn_mfma_f32_16x16x32_bf16(af, bfr, acc[n], 0, 0, 0);
      }
    }
  }
#pragma unroll
  for (int n = 0; n < 4; ++n) {
    const int gcol = n0 + n * 16 + (lane & 15);
    const int g = gcol >> 9, hh = gcol & 511;
    float badd = 0.0f;
    if (g == 0) badd = bi_x[hh] + bi_h[hh];
    else if (g == 1) badd = bf_x[hh] + bf_h[hh];
    const int rbase = m0 + w * 16 + (lane >> 4) * 4;
#pragma unroll
    for (int q = 0; q < 4; ++q) {
      Xpre[(size_t)(rbase + q) * 2048 + gcol] = f2bf(acc[n][q] + badd);
    }
  }
}

// ---------------------------------------------------------------------------
// Kernel 3: sequential recurrence, one cooperative launch, grid.sync per step.
// Grid = 64 WGs x 256 thr.  WG (band, ct): rows band*32..+31 (batch),
// cols ct*32..+31 (hidden).  Wave w computes gate w for the 32x32 tile.
// ---------------------------------------------------------------------------
__global__ __launch_bounds__(256) void treelstm_seq(
    const unsigned short* __restrict__ Xpre,  // [L*B][2048]
    const unsigned short* __restrict__ Wh,    // [4][512][512] bf16
    const int* __restrict__ parents,          // [L][B]
    float* __restrict__ Hout,                 // [B][L][H]  (d_out)
    float* __restrict__ Cbuf,                 // [B][L][H]
    unsigned short* __restrict__ Hbf) {       // [B][L][H] bf16
  cg::grid_group grid = cg::this_grid();
  __shared__ unsigned short phs[32][536];     // stride 1072B: aligned + conflict-free
  __shared__ float gbuf[4][32][33];
  const int tid = threadIdx.x;
  const int lane = tid & 63, w = tid >> 6;
  const int band = blockIdx.x >> 4;   // 0..3 -> batch rows
  const int ct = blockIdx.x & 15;     // 0..15 -> hidden cols
  const int c0 = ct * 32;

  for (int t = 0; t < LL; ++t) {
    if (t > 0) {
      __threadfence();
      grid.sync();
    }
    // gather parent h (bf16) into LDS
    {
      const int r = tid >> 3;   // 0..31
      const int q = tid & 7;    // 0..7, 64 bf16 each
      const int b = band * 32 + r;
      const int p = parents[t * BB + b];
      if (p >= 0) {
        const unsigned short* src = Hbf + ((size_t)b * LL + p) * HHH + q * 64;
#pragma unroll
        for (int j = 0; j < 8; ++j)
          *(u16x8*)&phs[r][q * 64 + j * 8] = ((const u16x8*)src)[j];
      } else {
        u16x8 z = {};
#pragma unroll
        for (int j = 0; j < 8; ++j) *(u16x8*)&phs[r][q * 64 + j * 8] = z;
      }
    }
    __syncthreads();
    // wave w: gate w, 32 rows x 32 cols, K = 512
    f32x4 acc[2][2] = {};
    const unsigned short* wgbase = Wh + (size_t)w * 512 * 512;
#pragma unroll 4
    for (int kk = 0; kk < 512; kk += 32) {
      const int ko = kk + 8 * (lane >> 4);
      bf16x8 a0 = *(const bf16x8*)&phs[lane & 15][ko];
      bf16x8 a1 = *(const bf16x8*)&phs[16 + (lane & 15)][ko];
      const unsigned short* bp0 = wgbase + (size_t)(c0 + (lane & 15)) * 512 + ko;
      bf16x8 b0 = *(const bf16x8*)bp0;
      bf16x8 b1 = *(const bf16x8*)(bp0 + 16 * 512);
      acc[0][0] = __builtin_amdgcn_mfma_f32_16x16x32_bf16(a0, b0, acc[0][0], 0, 0, 0);
      acc[1][0] = __builtin_amdgcn_mfma_f32_16x16x32_bf16(a1, b0, acc[1][0], 0, 0, 0);
      acc[0][1] = __builtin_amdgcn_mfma_f32_16x16x32_bf16(a0, b1, acc[0][1], 0, 0, 0);
      acc[1][1] = __builtin_amdgcn_mfma_f32_16x16x32_bf16(a1, b1, acc[1][1], 0, 0, 0);
    }
#pragma unroll
    for (int mi = 0; mi < 2; ++mi)
#pragma unroll
      for (int ni = 0; ni < 2; ++ni)
#pragma unroll
        for (int q = 0; q < 4; ++q)
          gbuf[w][mi * 16 + (lane >> 4) * 4 + q][ni * 16 + (lane & 15)] = acc[mi][ni][q];
    __syncthreads();
    // elementwise gates: thread -> (r, 4 cols)
    {
      const int r = tid >> 3;
      const int hc = (tid & 7) * 4;
      const int b = band * 32 + r;
      const int h = c0 + hc;
      const int p = parents[t * BB + b];
      const size_t xrow = ((size_t)t * BB + b) * 2048;
      float4 pc = make_float4(0.f, 0.f, 0.f, 0.f);
      if (p >= 0) pc = *(const float4*)(Cbuf + ((size_t)b * LL + p) * HHH + h);
      float xg[4][4];
#pragma unroll
      for (int g = 0; g < 4; ++g) {
        u16x4 xv = *(const u16x4*)(Xpre + xrow + g * 512 + h);
#pragma unroll
        for (int j = 0; j < 4; ++j) xg[g][j] = bf2f(xv[j]);
      }
      const float pcv[4] = {pc.x, pc.y, pc.z, pc.w};
      float cva[4], hva[4];
#pragma unroll
      for (int j = 0; j < 4; ++j) {
        float iv = sigm(gbuf[0][r][hc + j] + xg[0][j]);
        float fv = sigm(gbuf[1][r][hc + j] + xg[1][j]);
        float ov = sigm(gbuf[2][r][hc + j] + xg[2][j]);
        float uv = tanh_f(gbuf[3][r][hc + j] + xg[3][j]);
        float cv = iv * uv + fv * pcv[j];
        cva[j] = cv;
        hva[j] = ov * tanh_f(cv);
      }
      const size_t obase = ((size_t)b * LL + t) * HHH + h;
      *(float4*)(Cbuf + obase) = make_float4(cva[0], cva[1], cva[2], cva[3]);
      *(float4*)(Hout + obase) = make_float4(hva[0], hva[1], hva[2], hva[3]);
      u16x4 hb;
      hb[0] = f2bf(hva[0]); hb[1] = f2bf(hva[1]);
      hb[2] = f2bf(hva[2]); hb[3] = f2bf(hva[3]);
      *(u16x4*)(Hbf + obase) = hb;
    }
  }
}

// ---------------------------------------------------------------------------
extern "C" void kernel_launch(void* const* d_in, const int* in_sizes, int n_in,
                              void* d_out, int out_size, void* d_ws, size_t ws_size,
                              hipStream_t stream) {
  const float* X    = (const float*)d_in[0];
  const float* Wi_x = (const float*)d_in[1];
  const float* bi_x = (const float*)d_in[2];
  const float* Wi_h = (const float*)d_in[3];
  const float* bi_h = (const float*)d_in[4];
  const float* Wf_x = (const float*)d_in[5];
  const float* bf_x = (const float*)d_in[6];
  const float* Wf_h = (const float*)d_in[7];
  const float* bf_h = (const float*)d_in[8];
  const float* Wo_x = (const float*)d_in[9];
  const float* Wo_h = (const float*)d_in[10];
  const float* Wu_x = (const float*)d_in[11];
  const float* Wu_h = (const float*)d_in[12];
  const int* parents = (const int*)d_in[13];
  float* Hout = (float*)d_out;

  char* ws = (char*)d_ws;
  unsigned short* Xpre = (unsigned short*)ws; ws += (size_t)32768 * 2048 * 2;  // 128 MB
  unsigned short* Hbf  = (unsigned short*)ws; ws += (size_t)BB * LL * HHH * 2; // 32 MB
  float*          Cbuf = (float*)ws;          ws += (size_t)BB * LL * HHH * 4; // 64 MB
  unsigned short* Wxbf = (unsigned short*)ws; ws += (size_t)2048 * 512 * 2;    // 2 MB
  unsigned short* Whbf = (unsigned short*)ws; ws += (size_t)2048 * 512 * 2;    // 2 MB

  wcast<<<2048, 256, 0, stream>>>(Wi_x, Wf_x, Wo_x, Wu_x, Wi_h, Wf_h, Wo_h, Wu_h,
                                  Wxbf, Whbf);
  dim3 g1(512, 32);
  xproj<<<g1, 256, 0, stream>>>(X, Wxbf, bi_x, bi_h, bf_x, bf_h, Xpre);

  void* kargs[] = {(void*)&Xpre, (void*)&Whbf, (void*)&parents,
                   (void*)&Hout, (void*)&Cbuf, (void*)&Hbf};
  hipLaunchCooperativeKernel((void*)treelstm_seq, dim3(64), dim3(256), kargs, 0, stream);
}

// Round 2
// 3124.585 us; speedup vs baseline: 1.7669x; 1.7669x over previous
//
#include <hip/hip_runtime.h>
#include <hip/hip_bf16.h>
#include <hip/hip_cooperative_groups.h>

namespace cg = cooperative_groups;

static constexpr int LL = 256;   // sequence length / nodes
static constexpr int BB = 128;   // batch
static constexpr int HHH = 512;  // hidden dim

typedef __attribute__((ext_vector_type(8))) short bf16x8;
typedef __attribute__((ext_vector_type(4))) float f32x4;
typedef __attribute__((ext_vector_type(8))) unsigned short u16x8;
typedef __attribute__((ext_vector_type(4))) unsigned short u16x4;

__device__ __forceinline__ unsigned short f2bf(float f) {
  union { float f; unsigned u; } v; v.f = f;
  unsigned r = (v.u + 0x7FFFu + ((v.u >> 16) & 1u)) >> 16;
  return (unsigned short)r;
}
__device__ __forceinline__ float bf2f(unsigned short s) {
  union { unsigned u; float f; } v; v.u = ((unsigned)s) << 16;
  return v.f;
}
__device__ __forceinline__ float sigm(float x) { return 1.0f / (1.0f + __expf(-x)); }
__device__ __forceinline__ float tanh_f(float x) { return 1.0f - 2.0f / (__expf(2.0f * x) + 1.0f); }

// ---------------------------------------------------------------------------
// Kernel 1a: cast the 4 x-weight matrices to bf16 (row-major, K-major rows).
// ---------------------------------------------------------------------------
__global__ __launch_bounds__(256) void wcast4(
    const float* __restrict__ s0, const float* __restrict__ s1,
    const float* __restrict__ s2, const float* __restrict__ s3,
    unsigned short* __restrict__ wx) {
  int gid = blockIdx.x * 256 + threadIdx.x;
  int e = gid * 4;
  int m = e >> 18;            // which of 4 matrices (512*512 elems each)
  int off = e & 0x3FFFF;
  const float* srcs[4] = {s0, s1, s2, s3};
  float4 v = *(const float4*)(srcs[m] + off);
  u16x4 o;
  o[0] = f2bf(v.x); o[1] = f2bf(v.y); o[2] = f2bf(v.z); o[3] = f2bf(v.w);
  *(u16x4*)(wx + (size_t)m * 262144 + off) = o;
}

// ---------------------------------------------------------------------------
// Kernel 1b: pack the 4 h-weight matrices into MFMA B-fragment order (bf16).
// Whp block id = (g*32 + n16)*16 + kb, each block = 64 lanes * 8 bf16 = 1KB
// contiguous; lane l holds W[g][n16*16 + (l&15)][kb*32 + (l>>4)*8 + 0..7].
// ---------------------------------------------------------------------------
__global__ __launch_bounds__(256) void whpack(
    const float* __restrict__ Wi_h, const float* __restrict__ Wf_h,
    const float* __restrict__ Wo_h, const float* __restrict__ Wu_h,
    unsigned short* __restrict__ Whp) {
  int gid = blockIdx.x * 256 + threadIdx.x;   // 131072 threads total
  int lane = gid & 63;
  int kb   = (gid >> 6) & 15;
  int n16  = (gid >> 10) & 31;
  int g    = gid >> 15;
  const float* W = (g == 0) ? Wi_h : (g == 1) ? Wf_h : (g == 2) ? Wo_h : Wu_h;
  int row = n16 * 16 + (lane & 15);
  int col = kb * 32 + (lane >> 4) * 8;
  const float4* s = (const float4*)(W + (size_t)row * 512 + col);
  float4 v0 = s[0], v1 = s[1];
  u16x8 o;
  o[0] = f2bf(v0.x); o[1] = f2bf(v0.y); o[2] = f2bf(v0.z); o[3] = f2bf(v0.w);
  o[4] = f2bf(v1.x); o[5] = f2bf(v1.y); o[6] = f2bf(v1.z); o[7] = f2bf(v1.w);
  *(u16x8*)&Whp[(size_t)gid * 8] = o;
}

// ---------------------------------------------------------------------------
// Kernel 2: level assignment + bucketing.  One block, 128 threads (one per
// batch column).  Each thread walks t=0..255 (parent < t always), computes
// level[t] = level[parent]+1, counts per (b,level) without atomics, then
// scatters node ids (t*128+b) into `pairs` grouped by level.
// lmeta[0] = nlevels; lmeta[1+l] = start offset of level l (l=0..128).
// ---------------------------------------------------------------------------
__global__ __launch_bounds__(128) void levels_k(
    const int* __restrict__ parents, int* __restrict__ pairs,
    int* __restrict__ lmeta) {
  __shared__ unsigned short cnt2[128][130];  // per (b, level) counts -> starts
  __shared__ int off[130];
  __shared__ int maxl_sh;
  const int b = threadIdx.x;
  unsigned char mylvl[256];                  // private (scratch) per-column levels
  for (int l = 0; l < 130; ++l) cnt2[b][l] = 0;
  if (b == 0) maxl_sh = 0;
  __syncthreads();
  int maxl = 0;
  for (int t = 0; t < 256; ++t) {
    int p = parents[t * 128 + b];
    int l = (p < 0) ? 0 : (mylvl[p] + 1);
    if (l > 127) l = 127;                    // safety clamp (never hit for L=256 random tree depth)
    mylvl[t] = (unsigned char)l;
    maxl = l > maxl ? l : maxl;
    cnt2[b][l]++;
  }
  atomicMax(&maxl_sh, maxl);
  __syncthreads();
  const int nlev = maxl_sh + 1;
  // per-level totals (thread l sums over b)
  {
    int l = b;
    int s = 0;
    if (l < nlev) for (int bb = 0; bb < 128; ++bb) s += cnt2[bb][l];
    off[l + 1] = s;
  }
  __syncthreads();
  if (b == 0) {
    off[0] = 0;
    for (int l = 0; l < 128; ++l) off[l + 1] += off[l];
  }
  __syncthreads();
  // convert cnt2[:,l] into start positions (thread l, running prefix over b)
  {
    int l = b;
    if (l < nlev) {
      int run = off[l];
      for (int bb = 0; bb < 128; ++bb) {
        int c = cnt2[bb][l];
        cnt2[bb][l] = (unsigned short)run;
        run += c;
      }
    }
  }
  __syncthreads();
  for (int t = 0; t < 256; ++t) {
    int l = mylvl[t];
    int pos = cnt2[b][l]++;
    pairs[pos] = t * 128 + b;
  }
  if (b == 0) {
    lmeta[0] = nlev;
    for (int l = 0; l <= 128; ++l) lmeta[1 + l] = off[l];
  }
}

// ---------------------------------------------------------------------------
// Kernel 3: Xpre[t*B+b][g*512+h] = x[t,b,:] . Wg_x[h,:] + bias_g[h]   (bf16)
// GEMM M=32768 N=2048 K=512.  64x64 tile, BK=64, 4 waves.
// ---------------------------------------------------------------------------
__global__ __launch_bounds__(256) void xproj(
    const float* __restrict__ X, const unsigned short* __restrict__ Wx,
    const float* __restrict__ bi_x, const float* __restrict__ bi_h,
    const float* __restrict__ bf_x, const float* __restrict__ bf_h,
    unsigned short* __restrict__ Xpre) {
  __shared__ unsigned short As[64][72];
  __shared__ unsigned short Bs[64][72];
  const int m0 = blockIdx.x * 64;
  const int n0 = blockIdx.y * 64;
  const int tid = threadIdx.x;
  const int r = tid >> 2, c4 = tid & 3;
  const int lane = tid & 63, w = tid >> 6;
  f32x4 acc[4] = {};
  for (int kt = 0; kt < 8; ++kt) {
    const int k0 = kt * 64;
    __syncthreads();
    {
      const float* src = X + (size_t)(m0 + r) * 512 + k0 + c4 * 16;
      float4 v0 = ((const float4*)src)[0];
      float4 v1 = ((const float4*)src)[1];
      float4 v2 = ((const float4*)src)[2];
      float4 v3 = ((const float4*)src)[3];
      u16x8 p0, p1;
      p0[0] = f2bf(v0.x); p0[1] = f2bf(v0.y); p0[2] = f2bf(v0.z); p0[3] = f2bf(v0.w);
      p0[4] = f2bf(v1.x); p0[5] = f2bf(v1.y); p0[6] = f2bf(v1.z); p0[7] = f2bf(v1.w);
      p1[0] = f2bf(v2.x); p1[1] = f2bf(v2.y); p1[2] = f2bf(v2.z); p1[3] = f2bf(v2.w);
      p1[4] = f2bf(v3.x); p1[5] = f2bf(v3.y); p1[6] = f2bf(v3.z); p1[7] = f2bf(v3.w);
      *(u16x8*)&As[r][c4 * 16] = p0;
      *(u16x8*)&As[r][c4 * 16 + 8] = p1;
      const unsigned short* sb = Wx + (size_t)(n0 + r) * 512 + k0 + c4 * 16;
      u16x8 q0 = ((const u16x8*)sb)[0];
      u16x8 q1 = ((const u16x8*)sb)[1];
      *(u16x8*)&Bs[r][c4 * 16] = q0;
      *(u16x8*)&Bs[r][c4 * 16 + 8] = q1;
    }
    __syncthreads();
#pragma unroll
    for (int kk = 0; kk < 64; kk += 32) {
      const int ko = kk + 8 * (lane >> 4);
      bf16x8 af = *(const bf16x8*)&As[w * 16 + (lane & 15)][ko];
#pragma unroll
      for (int n = 0; n < 4; ++n) {
        bf16x8 bfr = *(const bf16x8*)&Bs[n * 16 + (lane & 15)][ko];
        acc[n] = __builtin_amdgcn_mfma_f32_16x16x32_bf16(af, bfr, acc[n], 0, 0, 0);
      }
    }
  }
#pragma unroll
  for (int n = 0; n < 4; ++n) {
    const int gcol = n0 + n * 16 + (lane & 15);
    const int g = gcol >> 9, hh = gcol & 511;
    float badd = 0.0f;
    if (g == 0) badd = bi_x[hh] + bi_h[hh];
    else if (g == 1) badd = bf_x[hh] + bf_h[hh];
    const int rbase = m0 + w * 16 + (lane >> 4) * 4;
#pragma unroll
    for (int q = 0; q < 4; ++q) {
      Xpre[(size_t)(rbase + q) * 2048 + gcol] = f2bf(acc[n][q] + badd);
    }
  }
}

// ---------------------------------------------------------------------------
// Kernel 4: level-parallel recurrence.  Persistent cooperative grid (768 WGs
// = 3/CU at 51.2KB LDS), ONE grid.sync per tree level (~16 total).
// Per level: tiles = ceil(cnt/32) * 16; tile = 32 gathered rows x 32 hidden
// cols x all 4 gates (wave w = gate w), K = 512.  B-operand from packed Whp
// (contiguous 1KB per wave per k-iter).
// ---------------------------------------------------------------------------
__global__ __launch_bounds__(256) void treelstm_lvl(
    const unsigned short* __restrict__ Xpre,  // [L*B][2048]
    const unsigned short* __restrict__ Whp,   // packed [4][32][16][512]
    const int* __restrict__ parents,          // [L][B]
    const int* __restrict__ pairs,            // [32768] node ids grouped by level
    const int* __restrict__ lmeta,            // [0]=nlev, [1+l]=offset
    float* __restrict__ Hout,                 // [B][L][H]  (d_out)
    float* __restrict__ Cbuf,                 // [B][L][H]
    unsigned short* __restrict__ Hbf) {       // [B][L][H] bf16
  cg::grid_group grid = cg::this_grid();
  __shared__ unsigned short phs[32][536];     // 34.3KB, conflict-safe stride
  __shared__ float gbuf[4][32][33];           // 16.9KB
  const int tid = threadIdx.x;
  const int lane = tid & 63, w = tid >> 6;
  const int nlev = lmeta[0];

  for (int lvl = 0; lvl < nlev; ++lvl) {
    const int off0 = lmeta[1 + lvl];
    const int cnt = lmeta[2 + lvl] - off0;
    const int ntiles = ((cnt + 31) >> 5) * 16;
    for (int tile = blockIdx.x; tile < ntiles; tile += gridDim.x) {
      const int mt = tile >> 4;
      const int ct = tile & 15;
      const int c0 = ct * 32;
      const int rbase = off0 + mt * 32;
      const int rcnt = min(32, cnt - mt * 32);
      __syncthreads();   // protect phs/gbuf from previous tile's readers
      // gather parent h rows (bf16) into LDS; zero rows beyond count
      {
        const int r = tid >> 3;   // 0..31
        const int q = tid & 7;    // 64 bf16 each
        int p = -1, b = 0;
        if (r < rcnt) {
          const int node = pairs[rbase + r];
          p = parents[node];
          b = node & 127;
        }
        if (p >= 0) {
          const unsigned short* src = Hbf + ((size_t)b * LL + p) * HHH + q * 64;
#pragma unroll
          for (int j = 0; j < 8; ++j)
            *(u16x8*)&phs[r][q * 64 + j * 8] = ((const u16x8*)src)[j];
        } else {
          u16x8 z = {};
#pragma unroll
          for (int j = 0; j < 8; ++j) *(u16x8*)&phs[r][q * 64 + j * 8] = z;
        }
      }
      __syncthreads();
      // wave w: gate w, 32 rows x 32 cols, K = 512
      f32x4 acc[2][2] = {};
      const int nbase = (w * 32 + ct * 2) * 16;
#pragma unroll 4
      for (int kb = 0; kb < 16; ++kb) {
        const int ko = kb * 32 + 8 * (lane >> 4);
        bf16x8 a0 = *(const bf16x8*)&phs[lane & 15][ko];
        bf16x8 a1 = *(const bf16x8*)&phs[16 + (lane & 15)][ko];
        bf16x8 b0 = *(const bf16x8*)&Whp[(size_t)(nbase + kb) * 512 + lane * 8];
        bf16x8 b1 = *(const bf16x8*)&Whp[(size_t)(nbase + 16 + kb) * 512 + lane * 8];
        acc[0][0] = __builtin_amdgcn_mfma_f32_16x16x32_bf16(a0, b0, acc[0][0], 0, 0, 0);
        acc[1][0] = __builtin_amdgcn_mfma_f32_16x16x32_bf16(a1, b0, acc[1][0], 0, 0, 0);
        acc[0][1] = __builtin_amdgcn_mfma_f32_16x16x32_bf16(a0, b1, acc[0][1], 0, 0, 0);
        acc[1][1] = __builtin_amdgcn_mfma_f32_16x16x32_bf16(a1, b1, acc[1][1], 0, 0, 0);
      }
#pragma unroll
      for (int mi = 0; mi < 2; ++mi)
#pragma unroll
        for (int ni = 0; ni < 2; ++ni)
#pragma unroll
          for (int q = 0; q < 4; ++q)
            gbuf[w][mi * 16 + (lane >> 4) * 4 + q][ni * 16 + (lane & 15)] = acc[mi][ni][q];
      __syncthreads();
      // elementwise gates: thread -> (row r, 4 hidden cols)
      {
        const int r = tid >> 3;
        const int hc = (tid & 7) * 4;
        if (r < rcnt) {
          const int node = pairs[rbase + r];
          const int b = node & 127;
          const int t = node >> 7;
          const int h = c0 + hc;
          const int p = parents[node];
          float4 pc = make_float4(0.f, 0.f, 0.f, 0.f);
          if (p >= 0) pc = *(const float4*)(Cbuf + ((size_t)b * LL + p) * HHH + h);
          float xg[4][4];
#pragma unroll
          for (int g = 0; g < 4; ++g) {
            u16x4 xv = *(const u16x4*)(Xpre + (size_t)node * 2048 + g * 512 + h);
#pragma unroll
            for (int j = 0; j < 4; ++j) xg[g][j] = bf2f(xv[j]);
          }
          const float pcv[4] = {pc.x, pc.y, pc.z, pc.w};
          float cva[4], hva[4];
#pragma unroll
          for (int j = 0; j < 4; ++j) {
            float iv = sigm(gbuf[0][r][hc + j] + xg[0][j]);
            float fv = sigm(gbuf[1][r][hc + j] + xg[1][j]);
            float ov = sigm(gbuf[2][r][hc + j] + xg[2][j]);
            float uv = tanh_f(gbuf[3][r][hc + j] + xg[3][j]);
            float cv = iv * uv + fv * pcv[j];
            cva[j] = cv;
            hva[j] = ov * tanh_f(cv);
          }
          const size_t obase = ((size_t)b * LL + t) * HHH + h;
          *(float4*)(Cbuf + obase) = make_float4(cva[0], cva[1], cva[2], cva[3]);
          *(float4*)(Hout + obase) = make_float4(hva[0], hva[1], hva[2], hva[3]);
          u16x4 hb;
          hb[0] = f2bf(hva[0]); hb[1] = f2bf(hva[1]);
          hb[2] = f2bf(hva[2]); hb[3] = f2bf(hva[3]);
          *(u16x4*)(Hbf + obase) = hb;
        }
      }
    }
    __threadfence();
    grid.sync();
  }
}

// ---------------------------------------------------------------------------
extern "C" void kernel_launch(void* const* d_in, const int* in_sizes, int n_in,
                              void* d_out, int out_size, void* d_ws, size_t ws_size,
                              hipStream_t stream) {
  const float* X    = (const float*)d_in[0];
  const float* Wi_x = (const float*)d_in[1];
  const float* bi_x = (const float*)d_in[2];
  const float* Wi_h = (const float*)d_in[3];
  const float* bi_h = (const float*)d_in[4];
  const float* Wf_x = (const float*)d_in[5];
  const float* bf_x = (const float*)d_in[6];
  const float* Wf_h = (const float*)d_in[7];
  const float* bf_h = (const float*)d_in[8];
  const float* Wo_x = (const float*)d_in[9];
  const float* Wo_h = (const float*)d_in[10];
  const float* Wu_x = (const float*)d_in[11];
  const float* Wu_h = (const float*)d_in[12];
  const int* parents = (const int*)d_in[13];
  float* Hout = (float*)d_out;

  char* ws = (char*)d_ws;
  unsigned short* Xpre = (unsigned short*)ws; ws += (size_t)32768 * 2048 * 2;  // 128 MB
  unsigned short* Hbf  = (unsigned short*)ws; ws += (size_t)BB * LL * HHH * 2; // 32 MB
  float*          Cbuf = (float*)ws;          ws += (size_t)BB * LL * HHH * 4; // 64 MB
  unsigned short* Wxbf = (unsigned short*)ws; ws += (size_t)2048 * 512 * 2;    // 2 MB
  unsigned short* Whp  = (unsigned short*)ws; ws += (size_t)2048 * 512 * 2;    // 2 MB
  int*            pairs = (int*)ws;           ws += (size_t)32768 * 4;         // 128 KB
  int*            lmeta = (int*)ws;           ws += 256 * 4;

  wcast4<<<1024, 256, 0, stream>>>(Wi_x, Wf_x, Wo_x, Wu_x, Wxbf);
  whpack<<<512, 256, 0, stream>>>(Wi_h, Wf_h, Wo_h, Wu_h, Whp);
  levels_k<<<1, 128, 0, stream>>>(parents, pairs, lmeta);
  dim3 g1(512, 32);
  xproj<<<g1, 256, 0, stream>>>(X, Wxbf, bi_x, bi_h, bf_x, bf_h, Xpre);

  void* kargs[] = {(void*)&Xpre, (void*)&Whp, (void*)&parents, (void*)&pairs,
                   (void*)&lmeta, (void*)&Hout, (void*)&Cbuf, (void*)&Hbf};
  hipLaunchCooperativeKernel((void*)treelstm_lvl, dim3(768), dim3(256), kargs, 0, stream);
}